// Round 1
// baseline (1377.292 us; speedup 1.0000x reference)
//
#include <hip/hip_runtime.h>
#include <hip/hip_bf16.h>
#include <stdint.h>

#define N_TOK 2048
#define HID   2048
#define NEXP  8
#define DFF   1408

typedef __attribute__((ext_vector_type(8))) short short8;
typedef __attribute__((ext_vector_type(4))) float f32x4;

__device__ __forceinline__ unsigned short f2bf(float f) {
  union { float ff; uint32_t u; } v; v.ff = f;
  return (unsigned short)((v.u + 0x7FFFu + ((v.u >> 16) & 1u)) >> 16);
}

// ---------------- K1: gating (fp32 logits -> softmax -> top2) ----------------
__global__ __launch_bounds__(256) void gate_topk_k(
    const float* __restrict__ h, const float* __restrict__ gw,
    int* __restrict__ cnt, int* __restrict__ topk_idx, float* __restrict__ topk_w)
{
  int token = blockIdx.x * 4 + (threadIdx.x >> 6);
  int lane  = threadIdx.x & 63;
  const float* hr = h + (size_t)token * HID;
  float acc[NEXP];
#pragma unroll
  for (int e = 0; e < NEXP; ++e) acc[e] = 0.f;
  for (int i = lane; i < HID; i += 64) {
    float hv = hr[i];
#pragma unroll
    for (int e = 0; e < NEXP; ++e) acc[e] = fmaf(hv, gw[e * HID + i], acc[e]);
  }
#pragma unroll
  for (int e = 0; e < NEXP; ++e) {
    float a = acc[e];
#pragma unroll
    for (int s = 32; s > 0; s >>= 1) a += __shfl_xor(a, s, 64);
    acc[e] = a;
  }
  if (lane == 0) {
    float m = acc[0];
#pragma unroll
    for (int e = 1; e < NEXP; ++e) m = fmaxf(m, acc[e]);
    float w[NEXP]; float s = 0.f;
#pragma unroll
    for (int e = 0; e < NEXP; ++e) { w[e] = __expf(acc[e] - m); s += w[e]; }
    float inv = 1.f / s;
    int i0 = 0; float b0 = acc[0];
#pragma unroll
    for (int e = 1; e < NEXP; ++e) if (acc[e] > b0) { b0 = acc[e]; i0 = e; }
    int i1 = -1; float b1 = -3.4e38f;
#pragma unroll
    for (int e = 0; e < NEXP; ++e) if (e != i0 && acc[e] > b1) { b1 = acc[e]; i1 = e; }
    topk_idx[token * 2 + 0] = i0;
    topk_idx[token * 2 + 1] = i1;
    topk_w[token * 2 + 0] = w[i0] * inv;
    topk_w[token * 2 + 1] = w[i1] * inv;
    atomicAdd(&cnt[i0], 1);
    atomicAdd(&cnt[i1], 1);
  }
}

// ---------------- K2: prefix-sum of expert counts ----------------
__global__ void prefix_k(const int* __restrict__ cnt, int* __restrict__ offs,
                         int* __restrict__ cursor) {
  if (threadIdx.x == 0 && blockIdx.x == 0) {
    int s = 0;
    for (int e = 0; e < NEXP; ++e) { offs[e] = s; cursor[e] = s; s += cnt[e]; }
  }
}

// ---------------- K3: scatter token->pair lists ----------------
__global__ __launch_bounds__(256) void scatter_k(
    const int* __restrict__ topk_idx, const float* __restrict__ topk_w,
    int* __restrict__ cursor, int* __restrict__ pair_token, float* __restrict__ pair_w)
{
  int n = blockIdx.x * 256 + threadIdx.x;
  if (n >= N_TOK) return;
#pragma unroll
  for (int k = 0; k < 2; ++k) {
    int e = topk_idx[n * 2 + k];
    int p = atomicAdd(&cursor[e], 1);
    pair_token[p] = n;
    pair_w[p] = topk_w[n * 2 + k];
  }
}

// ---------------- K4: grouped GEMM gate+up, fused SwiGLU -> act (bf16) ----------------
// tile 128(tokens) x 128(f), BK=32. 4 waves, each 64x64 quadrant of 16x16x32 frags.
__global__ __launch_bounds__(256) void gateup_k(
    const float* __restrict__ h, const float* __restrict__ wg_, const float* __restrict__ wu_,
    const int* __restrict__ cnt, const int* __restrict__ offs,
    const int* __restrict__ pair_token, unsigned short* __restrict__ act)
{
  const int e = blockIdx.z, mb = blockIdx.x, nb = blockIdx.y;
  const int count = cnt[e];
  if (mb * 128 >= count) return;
  const int off = offs[e];
  const int rows = min(128, count - mb * 128);
  const int c0 = nb * 128;

  __shared__ unsigned short As[128 * 40];   // [row][k] pad-40
  __shared__ unsigned short Bg[128 * 40];   // [f][k]  pad-40 (transposed)
  __shared__ unsigned short Bu[128 * 40];
  __shared__ int tok[128];

  const int t = threadIdx.x;
  if (t < 128) tok[t] = pair_token[off + mb * 128 + min(t, rows - 1)];
  __syncthreads();

  // A staging: thread -> (row = t>>1, k-half = (t&1)*16), 4x float4
  const int ra = t >> 1, ka = (t & 1) * 16;
  const float* aRow = h + (size_t)tok[ra] * HID + ka;
  // B staging: thread -> (k-row kb = t>>3, f-group fo = (t&7)*16), 4x float4 each
  const int kb = t >> 3, fo = (t & 7) * 16;
  const float* gRow = wg_ + (size_t)e * HID * DFF + (size_t)kb * DFF + c0 + fo;
  const float* uRow = wu_ + (size_t)e * HID * DFF + (size_t)kb * DFF + c0 + fo;

  const int wid = t >> 6, lane = t & 63;
  const int wr = (wid >> 1) * 64, wc = (wid & 1) * 64;
  const int fr = lane & 15, fq = lane >> 4;

  f32x4 accg[4][4], accu[4][4];
#pragma unroll
  for (int i = 0; i < 4; ++i)
#pragma unroll
    for (int j = 0; j < 4; ++j) {
      accg[i][j] = (f32x4){0.f, 0.f, 0.f, 0.f};
      accu[i][j] = (f32x4){0.f, 0.f, 0.f, 0.f};
    }

  for (int kt = 0; kt < HID; kt += 32) {
#pragma unroll
    for (int i = 0; i < 4; ++i) {
      float4 va = *(const float4*)(aRow + kt + i * 4);
      ushort4 pa;
      pa.x = f2bf(va.x); pa.y = f2bf(va.y); pa.z = f2bf(va.z); pa.w = f2bf(va.w);
      *(ushort4*)&As[ra * 40 + ka + i * 4] = pa;
    }
    const float* gp = gRow + (size_t)kt * DFF;
    const float* up = uRow + (size_t)kt * DFF;
#pragma unroll
    for (int i = 0; i < 4; ++i) {
      float4 vg = *(const float4*)(gp + i * 4);
      float4 vu = *(const float4*)(up + i * 4);
      int fb = fo + i * 4;
      Bg[(fb + 0) * 40 + kb] = f2bf(vg.x); Bg[(fb + 1) * 40 + kb] = f2bf(vg.y);
      Bg[(fb + 2) * 40 + kb] = f2bf(vg.z); Bg[(fb + 3) * 40 + kb] = f2bf(vg.w);
      Bu[(fb + 0) * 40 + kb] = f2bf(vu.x); Bu[(fb + 1) * 40 + kb] = f2bf(vu.y);
      Bu[(fb + 2) * 40 + kb] = f2bf(vu.z); Bu[(fb + 3) * 40 + kb] = f2bf(vu.w);
    }
    __syncthreads();

    short8 af[4], bg[4], bu[4];
#pragma unroll
    for (int mi = 0; mi < 4; ++mi)
      af[mi] = *(const short8*)&As[(wr + mi * 16 + fr) * 40 + fq * 8];
#pragma unroll
    for (int ni = 0; ni < 4; ++ni) {
      bg[ni] = *(const short8*)&Bg[(wc + ni * 16 + fr) * 40 + fq * 8];
      bu[ni] = *(const short8*)&Bu[(wc + ni * 16 + fr) * 40 + fq * 8];
    }
#pragma unroll
    for (int mi = 0; mi < 4; ++mi)
#pragma unroll
      for (int ni = 0; ni < 4; ++ni) {
        accg[mi][ni] = __builtin_amdgcn_mfma_f32_16x16x32_bf16(af[mi], bg[ni], accg[mi][ni], 0, 0, 0);
        accu[mi][ni] = __builtin_amdgcn_mfma_f32_16x16x32_bf16(af[mi], bu[ni], accu[mi][ni], 0, 0, 0);
      }
    __syncthreads();
  }

  // epilogue: silu(g)*u -> bf16 act  (C/D layout: col=lane&15, row=(lane>>4)*4+j)
#pragma unroll
  for (int mi = 0; mi < 4; ++mi)
#pragma unroll
    for (int ni = 0; ni < 4; ++ni)
#pragma unroll
      for (int j = 0; j < 4; ++j) {
        int r = wr + mi * 16 + fq * 4 + j;
        if (r < rows) {
          float g = accg[mi][ni][j], u = accu[mi][ni][j];
          float a = (g / (1.f + __expf(-g))) * u;
          act[(size_t)(off + mb * 128 + r) * DFF + (c0 + wc + ni * 16 + fr)] = f2bf(a);
        }
      }
}

// ---------------- K5: grouped GEMM down, weighted atomic accumulate ----------------
__global__ __launch_bounds__(256) void down_k(
    const unsigned short* __restrict__ act, const float* __restrict__ wd_,
    const int* __restrict__ cnt, const int* __restrict__ offs,
    const int* __restrict__ pair_token, const float* __restrict__ pair_w,
    float* __restrict__ out)
{
  const int e = blockIdx.z, mb = blockIdx.x, nb = blockIdx.y;
  const int count = cnt[e];
  if (mb * 128 >= count) return;
  const int off = offs[e];
  const int rows = min(128, count - mb * 128);
  const int c0 = nb * 128;

  __shared__ unsigned short As[128 * 40];   // [pair-row][k] pad-40 (bf16 act)
  __shared__ unsigned short Bd[128 * 40];   // [d][f] pad-40 (transposed)
  __shared__ int tok2[128];
  __shared__ float twt[128];

  const int t = threadIdx.x;
  if (t < 128) {
    int rc = min(t, rows - 1);
    tok2[t] = pair_token[off + mb * 128 + rc];
    twt[t] = pair_w[off + mb * 128 + rc];
  }
  __syncthreads();

  // A staging: thread -> row = t>>1, two 16B chunks kc = (t&1)*2, +1
  const int rA = t >> 1, kc = (t & 1) * 2;
  const unsigned short* aRow = act + (size_t)(off + mb * 128 + min(rA, rows - 1)) * DFF;
  // B staging
  const int kb = t >> 3, fo = (t & 7) * 16;
  const float* dRow = wd_ + (size_t)e * DFF * HID + (size_t)kb * HID + c0 + fo;

  const int wid = t >> 6, lane = t & 63;
  const int wr = (wid >> 1) * 64, wc = (wid & 1) * 64;
  const int fr = lane & 15, fq = lane >> 4;

  f32x4 acc[4][4];
#pragma unroll
  for (int i = 0; i < 4; ++i)
#pragma unroll
    for (int j = 0; j < 4; ++j) acc[i][j] = (f32x4){0.f, 0.f, 0.f, 0.f};

  for (int kt = 0; kt < DFF; kt += 32) {
    *(uint4*)&As[rA * 40 + kc * 8]       = *(const uint4*)(aRow + kt + kc * 8);
    *(uint4*)&As[rA * 40 + (kc + 1) * 8] = *(const uint4*)(aRow + kt + (kc + 1) * 8);
    const float* dp = dRow + (size_t)kt * HID;
#pragma unroll
    for (int i = 0; i < 4; ++i) {
      float4 vd = *(const float4*)(dp + i * 4);
      int fb = fo + i * 4;
      Bd[(fb + 0) * 40 + kb] = f2bf(vd.x); Bd[(fb + 1) * 40 + kb] = f2bf(vd.y);
      Bd[(fb + 2) * 40 + kb] = f2bf(vd.z); Bd[(fb + 3) * 40 + kb] = f2bf(vd.w);
    }
    __syncthreads();

    short8 af[4], bd[4];
#pragma unroll
    for (int mi = 0; mi < 4; ++mi)
      af[mi] = *(const short8*)&As[(wr + mi * 16 + fr) * 40 + fq * 8];
#pragma unroll
    for (int ni = 0; ni < 4; ++ni)
      bd[ni] = *(const short8*)&Bd[(wc + ni * 16 + fr) * 40 + fq * 8];
#pragma unroll
    for (int mi = 0; mi < 4; ++mi)
#pragma unroll
      for (int ni = 0; ni < 4; ++ni)
        acc[mi][ni] = __builtin_amdgcn_mfma_f32_16x16x32_bf16(af[mi], bd[ni], acc[mi][ni], 0, 0, 0);
    __syncthreads();
  }

#pragma unroll
  for (int mi = 0; mi < 4; ++mi)
#pragma unroll
    for (int ni = 0; ni < 4; ++ni)
#pragma unroll
      for (int j = 0; j < 4; ++j) {
        int r = wr + mi * 16 + fq * 4 + j;
        if (r < rows) {
          float v = acc[mi][ni][j] * twt[r];
          atomicAdd(&out[(size_t)tok2[r] * HID + (c0 + wc + ni * 16 + fr)], v);
        }
      }
}

extern "C" void kernel_launch(void* const* d_in, const int* in_sizes, int n_in,
                              void* d_out, int out_size, void* d_ws, size_t ws_size,
                              hipStream_t stream) {
  const float* h  = (const float*)d_in[0];
  const float* gw = (const float*)d_in[1];
  const float* wg = (const float*)d_in[2];
  const float* wu = (const float*)d_in[3];
  const float* wd = (const float*)d_in[4];
  float* out = (float*)d_out;

  char* ws = (char*)d_ws;
  int*   cnt        = (int*)(ws + 0);
  int*   offs       = (int*)(ws + 32);
  int*   cursor     = (int*)(ws + 64);
  int*   pair_token = (int*)(ws + 256);
  float* pair_w     = (float*)(ws + 256 + 16384);
  int*   topk_idx   = (int*)(ws + 256 + 32768);
  float* topk_w     = (float*)(ws + 256 + 49152);
  unsigned short* act = (unsigned short*)(ws + 65792);  // 4096 x 1408 bf16 = 11.5 MB

  hipMemsetAsync(ws, 0, 256, stream);
  hipMemsetAsync(d_out, 0, (size_t)out_size * sizeof(float), stream);

  gate_topk_k<<<N_TOK / 4, 256, 0, stream>>>(h, gw, cnt, topk_idx, topk_w);
  prefix_k<<<1, 64, 0, stream>>>(cnt, offs, cursor);
  scatter_k<<<N_TOK / 256, 256, 0, stream>>>(topk_idx, topk_w, cursor, pair_token, pair_w);
  gateup_k<<<dim3(16, 11, 8), 256, 0, stream>>>(h, wg, wu, cnt, offs, pair_token, act);
  down_k<<<dim3(16, 16, 8), 256, 0, stream>>>(act, wd, cnt, offs, pair_token, pair_w, out);
}

// Round 2
// 569.016 us; speedup vs baseline: 2.4205x; 2.4205x over previous
//
#include <hip/hip_runtime.h>
#include <hip/hip_bf16.h>
#include <stdint.h>

#define N_TOK 2048
#define HID   2048
#define NEXP  8
#define DFF   1408

typedef __attribute__((ext_vector_type(8))) short short8;
typedef __attribute__((ext_vector_type(4))) float f32x4;

__device__ __forceinline__ unsigned short f2bf(float f) {
  union { float ff; uint32_t u; } v; v.ff = f;
  return (unsigned short)((v.u + 0x7FFFu + ((v.u >> 16) & 1u)) >> 16);
}

// async global->LDS, 16B per lane; LDS dest = base + lane*16 (wave-uniform base)
__device__ __forceinline__ void gl2lds16(const void* g, void* l) {
  __builtin_amdgcn_global_load_lds(
      (const __attribute__((address_space(1))) void*)g,
      (__attribute__((address_space(3))) void*)l, 16, 0, 0);
}

// ---------------- K1: gating (fp32 logits -> softmax -> top2) ----------------
__global__ __launch_bounds__(256) void gate_topk_k(
    const float* __restrict__ h, const float* __restrict__ gw,
    int* __restrict__ cnt, int* __restrict__ topk_idx, float* __restrict__ topk_w)
{
  int token = blockIdx.x * 4 + (threadIdx.x >> 6);
  int lane  = threadIdx.x & 63;
  const float* hr = h + (size_t)token * HID;
  float acc[NEXP];
#pragma unroll
  for (int e = 0; e < NEXP; ++e) acc[e] = 0.f;
  for (int i = lane; i < HID; i += 64) {
    float hv = hr[i];
#pragma unroll
    for (int e = 0; e < NEXP; ++e) acc[e] = fmaf(hv, gw[e * HID + i], acc[e]);
  }
#pragma unroll
  for (int e = 0; e < NEXP; ++e) {
    float a = acc[e];
#pragma unroll
    for (int s = 32; s > 0; s >>= 1) a += __shfl_xor(a, s, 64);
    acc[e] = a;
  }
  if (lane == 0) {
    float m = acc[0];
#pragma unroll
    for (int e = 1; e < NEXP; ++e) m = fmaxf(m, acc[e]);
    float w[NEXP]; float s = 0.f;
#pragma unroll
    for (int e = 0; e < NEXP; ++e) { w[e] = __expf(acc[e] - m); s += w[e]; }
    float inv = 1.f / s;
    int i0 = 0; float b0 = acc[0];
#pragma unroll
    for (int e = 1; e < NEXP; ++e) if (acc[e] > b0) { b0 = acc[e]; i0 = e; }
    int i1 = -1; float b1 = -3.4e38f;
#pragma unroll
    for (int e = 0; e < NEXP; ++e) if (e != i0 && acc[e] > b1) { b1 = acc[e]; i1 = e; }
    topk_idx[token * 2 + 0] = i0;
    topk_idx[token * 2 + 1] = i1;
    topk_w[token * 2 + 0] = w[i0] * inv;
    topk_w[token * 2 + 1] = w[i1] * inv;
    atomicAdd(&cnt[i0], 1);
    atomicAdd(&cnt[i1], 1);
  }
}

// ---------------- K2: prefix ----------------
__global__ void prefix_k(const int* __restrict__ cnt, int* __restrict__ offs,
                         int* __restrict__ cursor) {
  if (threadIdx.x == 0 && blockIdx.x == 0) {
    int s = 0;
    for (int e = 0; e < NEXP; ++e) { offs[e] = s; cursor[e] = s; s += cnt[e]; }
  }
}

// ---------------- K3: scatter ----------------
__global__ __launch_bounds__(256) void scatter_k(
    const int* __restrict__ topk_idx, const float* __restrict__ topk_w,
    int* __restrict__ cursor, int* __restrict__ pair_token, float* __restrict__ pair_w)
{
  int n = blockIdx.x * 256 + threadIdx.x;
  if (n >= N_TOK) return;
#pragma unroll
  for (int k = 0; k < 2; ++k) {
    int e = topk_idx[n * 2 + k];
    int p = atomicAdd(&cursor[e], 1);
    pair_token[p] = n;
    pair_w[p] = topk_w[n * 2 + k];
  }
}

// ---------------- K4: h fp32 -> bf16 ----------------
__global__ __launch_bounds__(256) void convert_h_k(const float* __restrict__ src,
                                                   unsigned short* __restrict__ dst) {
  int i = blockIdx.x * 256 + threadIdx.x;  // grid covers N_TOK*HID/8
  float4 a = ((const float4*)src)[(size_t)i * 2];
  float4 b = ((const float4*)src)[(size_t)i * 2 + 1];
  unsigned short o[8] = {f2bf(a.x), f2bf(a.y), f2bf(a.z), f2bf(a.w),
                         f2bf(b.x), f2bf(b.y), f2bf(b.z), f2bf(b.w)};
  *(short8*)&dst[(size_t)i * 8] = *(const short8*)o;
}

// ---------------- K5: transpose-convert  src fp32 [z][R][C] -> dst bf16 [z][C][R] ----------------
__global__ __launch_bounds__(256) void transpose_k(const float* __restrict__ src,
                                                   unsigned short* __restrict__ dst,
                                                   int R, int C)
{
  __shared__ unsigned short T[64 * 66];
  const size_t sl = (size_t)R * C;
  const float* s = src + blockIdx.z * sl;
  unsigned short* d = dst + blockIdx.z * sl;
  const int rb = blockIdx.x * 64, cb = blockIdx.y * 64;
  const int t = threadIdx.x;
  const int tr = t >> 4, tc = (t & 15) * 4;
  const float* sp = s + (size_t)(rb + tr) * C + cb + tc;
#pragma unroll
  for (int i = 0; i < 4; ++i) {
    float4 v = *(const float4*)(sp + (size_t)i * 16 * C);
    int r = tr + i * 16;
    uint32_t p0 = (uint32_t)f2bf(v.x) | ((uint32_t)f2bf(v.y) << 16);
    uint32_t p1 = (uint32_t)f2bf(v.z) | ((uint32_t)f2bf(v.w) << 16);
    *(uint32_t*)&T[r * 66 + tc]     = p0;
    *(uint32_t*)&T[r * 66 + tc + 2] = p1;
  }
  __syncthreads();
  const int f = t >> 2, ch = (t & 3) * 16;
  unsigned short* dp = d + (size_t)(cb + f) * R + rb + ch;
#pragma unroll
  for (int g = 0; g < 2; ++g) {
    unsigned short buf[8];
#pragma unroll
    for (int j = 0; j < 8; ++j) buf[j] = T[(ch + g * 8 + j) * 66 + f];
    *(short8*)(dp + g * 8) = *(const short8*)buf;
  }
}

// ---------------- K6: grouped GEMM gate+up (M128 x N128 x BK64, 8 waves) ----------------
// LDS rows are 64 bf16 (128B); global source chunk is XOR-swizzled so linear
// global_load_lds dest + swizzled ds_read_b128 is bank-conflict-floor (rule #21).
__global__ __launch_bounds__(512) void gateup2_k(
    const unsigned short* __restrict__ hbf,
    const unsigned short* __restrict__ wgt, const unsigned short* __restrict__ wut,
    const int* __restrict__ cnt, const int* __restrict__ offs,
    const int* __restrict__ pair_token, unsigned short* __restrict__ act,
    int e_base, size_t wstride)
{
  const int ez = blockIdx.z, e = e_base + ez;
  const int count = cnt[e], mb = blockIdx.x;
  if (mb * 128 >= count) return;
  const int off = offs[e];
  const int rows = min(128, count - mb * 128);
  const int c0 = blockIdx.y * 128;

  __shared__ unsigned short As[128 * 64];
  __shared__ unsigned short Bg[128 * 64];
  __shared__ unsigned short Bu[128 * 64];
  __shared__ int tok[128];

  const int t = threadIdx.x;
  if (t < 128) tok[t] = pair_token[off + mb * 128 + min(t, rows - 1)];
  __syncthreads();

  const int w = t >> 6, l = t & 63;
  const int sr = l >> 3;                       // 0..7 row-within-load
  const int sc = ((l & 7) ^ sr) * 8;           // swizzled source col (bf16 elems)
  const int r0 = w * 16 + sr, r1 = w * 16 + 8 + sr;

  const unsigned short* wgE = wgt + (size_t)ez * wstride;
  const unsigned short* wuE = wut + (size_t)ez * wstride;
  const unsigned short* aP0 = hbf + (size_t)tok[r0] * HID + sc;
  const unsigned short* aP1 = hbf + (size_t)tok[r1] * HID + sc;
  const unsigned short* gP0 = wgE + (size_t)(c0 + r0) * HID + sc;
  const unsigned short* gP1 = wgE + (size_t)(c0 + r1) * HID + sc;
  const unsigned short* uP0 = wuE + (size_t)(c0 + r0) * HID + sc;
  const unsigned short* uP1 = wuE + (size_t)(c0 + r1) * HID + sc;
  void* lA0 = &As[(w * 16) * 64];     void* lA1 = &As[(w * 16 + 8) * 64];
  void* lG0 = &Bg[(w * 16) * 64];     void* lG1 = &Bg[(w * 16 + 8) * 64];
  void* lU0 = &Bu[(w * 16) * 64];     void* lU1 = &Bu[(w * 16 + 8) * 64];

  const int fr = l & 15, fq = l >> 4;
  const int wr = (w >> 2) * 64, wc = (w & 3) * 32;
  const int f3 = fr & 7;

  f32x4 accg[4][2], accu[4][2];
#pragma unroll
  for (int i = 0; i < 4; ++i)
#pragma unroll
    for (int j = 0; j < 2; ++j) {
      accg[i][j] = (f32x4){0.f, 0.f, 0.f, 0.f};
      accu[i][j] = (f32x4){0.f, 0.f, 0.f, 0.f};
    }

  for (int kt = 0; kt < HID; kt += 64) {
    gl2lds16(aP0 + kt, lA0); gl2lds16(aP1 + kt, lA1);
    gl2lds16(gP0 + kt, lG0); gl2lds16(gP1 + kt, lG1);
    gl2lds16(uP0 + kt, lU0); gl2lds16(uP1 + kt, lU1);
    __syncthreads();

    short8 af[4][2], bg[2][2], bu[2][2];
#pragma unroll
    for (int kk = 0; kk < 2; ++kk) {
      const int ch = ((kk * 4 + fq) ^ f3) * 8;
#pragma unroll
      for (int mi = 0; mi < 4; ++mi)
        af[mi][kk] = *(const short8*)&As[(wr + mi * 16 + fr) * 64 + ch];
#pragma unroll
      for (int ni = 0; ni < 2; ++ni) {
        bg[ni][kk] = *(const short8*)&Bg[(wc + ni * 16 + fr) * 64 + ch];
        bu[ni][kk] = *(const short8*)&Bu[(wc + ni * 16 + fr) * 64 + ch];
      }
    }
#pragma unroll
    for (int kk = 0; kk < 2; ++kk)
#pragma unroll
      for (int mi = 0; mi < 4; ++mi)
#pragma unroll
        for (int ni = 0; ni < 2; ++ni) {
          accg[mi][ni] = __builtin_amdgcn_mfma_f32_16x16x32_bf16(af[mi][kk], bg[ni][kk], accg[mi][ni], 0, 0, 0);
          accu[mi][ni] = __builtin_amdgcn_mfma_f32_16x16x32_bf16(af[mi][kk], bu[ni][kk], accu[mi][ni], 0, 0, 0);
        }
    __syncthreads();
  }

#pragma unroll
  for (int mi = 0; mi < 4; ++mi)
#pragma unroll
    for (int ni = 0; ni < 2; ++ni)
#pragma unroll
      for (int j = 0; j < 4; ++j) {
        int r = wr + mi * 16 + fq * 4 + j;
        if (r < rows) {
          float g = accg[mi][ni][j], u = accu[mi][ni][j];
          float a = (g / (1.f + __expf(-g))) * u;
          act[(size_t)(off + mb * 128 + r) * DFF + (c0 + wc + ni * 16 + fr)] = f2bf(a);
        }
      }
}

// ---------------- K7: grouped GEMM down (M128 x N128 x BK64, 4 waves) ----------------
__global__ __launch_bounds__(256) void down2_k(
    const unsigned short* __restrict__ act, const unsigned short* __restrict__ wdt,
    const int* __restrict__ cnt, const int* __restrict__ offs,
    const int* __restrict__ pair_token, const float* __restrict__ pair_w,
    float* __restrict__ out, int e_base, size_t wstride)
{
  const int ez = blockIdx.z, e = e_base + ez;
  const int count = cnt[e], mb = blockIdx.x;
  if (mb * 128 >= count) return;
  const int off = offs[e];
  const int rows = min(128, count - mb * 128);
  const int c0 = blockIdx.y * 128;

  __shared__ unsigned short As[128 * 64];
  __shared__ unsigned short Bd[128 * 64];
  __shared__ int tok2[128];
  __shared__ float twt[128];

  const int t = threadIdx.x;
  if (t < 128) {
    int rc = min(t, rows - 1);
    tok2[t] = pair_token[off + mb * 128 + rc];
    twt[t] = pair_w[off + mb * 128 + rc];
  }
  __syncthreads();

  const int w = t >> 6, l = t & 63;
  const int sr = l >> 3;
  const int sc = ((l & 7) ^ sr) * 8;
  const unsigned short* wdE = wdt + (size_t)ez * wstride;

  const unsigned short* aP[4];
  const unsigned short* bP[4];
  void* lA[4]; void* lB[4];
#pragma unroll
  for (int i = 0; i < 4; ++i) {
    int rr = w * 32 + i * 8 + sr;   // 0..127
    aP[i] = act + (size_t)(off + mb * 128 + rr) * DFF + sc;
    bP[i] = wdE + (size_t)(c0 + rr) * DFF + sc;
    lA[i] = &As[rr * 64 - sr * 64]; // wave-uniform base: row block start
    lB[i] = &Bd[rr * 64 - sr * 64];
  }

  const int fr = l & 15, fq = l >> 4;
  const int wr = (w >> 1) * 64, wc = (w & 1) * 64;
  const int f3 = fr & 7;

  f32x4 acc[4][4];
#pragma unroll
  for (int i = 0; i < 4; ++i)
#pragma unroll
    for (int j = 0; j < 4; ++j) acc[i][j] = (f32x4){0.f, 0.f, 0.f, 0.f};

  for (int kt = 0; kt < DFF; kt += 64) {
#pragma unroll
    for (int i = 0; i < 4; ++i) { gl2lds16(aP[i] + kt, lA[i]); gl2lds16(bP[i] + kt, lB[i]); }
    __syncthreads();

    short8 af[4][2], bd[4][2];
#pragma unroll
    for (int kk = 0; kk < 2; ++kk) {
      const int ch = ((kk * 4 + fq) ^ f3) * 8;
#pragma unroll
      for (int mi = 0; mi < 4; ++mi)
        af[mi][kk] = *(const short8*)&As[(wr + mi * 16 + fr) * 64 + ch];
#pragma unroll
      for (int ni = 0; ni < 4; ++ni)
        bd[ni][kk] = *(const short8*)&Bd[(wc + ni * 16 + fr) * 64 + ch];
    }
#pragma unroll
    for (int kk = 0; kk < 2; ++kk)
#pragma unroll
      for (int mi = 0; mi < 4; ++mi)
#pragma unroll
        for (int ni = 0; ni < 4; ++ni)
          acc[mi][ni] = __builtin_amdgcn_mfma_f32_16x16x32_bf16(af[mi][kk], bd[ni][kk], acc[mi][ni], 0, 0, 0);
    __syncthreads();
  }

#pragma unroll
  for (int mi = 0; mi < 4; ++mi)
#pragma unroll
    for (int ni = 0; ni < 4; ++ni)
#pragma unroll
      for (int j = 0; j < 4; ++j) {
        int r = wr + mi * 16 + fq * 4 + j;
        if (r < rows) {
          float v = acc[mi][ni][j] * twt[r];
          atomicAdd(&out[(size_t)tok2[r] * HID + (c0 + wc + ni * 16 + fr)], v);
        }
      }
}

extern "C" void kernel_launch(void* const* d_in, const int* in_sizes, int n_in,
                              void* d_out, int out_size, void* d_ws, size_t ws_size,
                              hipStream_t stream) {
  const float* h  = (const float*)d_in[0];
  const float* gw = (const float*)d_in[1];
  const float* wg = (const float*)d_in[2];
  const float* wu = (const float*)d_in[3];
  const float* wd = (const float*)d_in[4];
  float* out = (float*)d_out;

  const size_t SL = (size_t)DFF * HID;          // weight slice elements
  char* ws = (char*)d_ws;
  int*   cnt        = (int*)(ws + 0);
  int*   offs       = (int*)(ws + 32);
  int*   cursor     = (int*)(ws + 64);
  int*   pair_token = (int*)(ws + 256);
  float* pair_w     = (float*)(ws + 256 + 16384);
  int*   topk_idx   = (int*)(ws + 33024);
  float* topk_w     = (float*)(ws + 49408);
  unsigned short* act = (unsigned short*)(ws + 65792);                 // 11,534,336 B
  unsigned short* hbf = (unsigned short*)(ws + 11600128);              //  8,388,608 B
  unsigned short* wgt = (unsigned short*)(ws + 19988736);              // 46,137,344 B (also wdt)
  unsigned short* wut = (unsigned short*)(ws + 66126080);              // 46,137,344 B -> 112,263,424
  const size_t NEED_FULL = 112263424ull;

  hipMemsetAsync(ws, 0, 256, stream);
  hipMemsetAsync(d_out, 0, (size_t)out_size * sizeof(float), stream);

  gate_topk_k<<<N_TOK / 4, 256, 0, stream>>>(h, gw, cnt, topk_idx, topk_w);
  prefix_k<<<1, 64, 0, stream>>>(cnt, offs, cursor);
  scatter_k<<<N_TOK / 256, 256, 0, stream>>>(topk_idx, topk_w, cursor, pair_token, pair_w);
  convert_h_k<<<(N_TOK * HID / 8) / 256, 256, 0, stream>>>(h, hbf);

  if (ws_size >= NEED_FULL) {
    transpose_k<<<dim3(HID / 64, DFF / 64, 8), 256, 0, stream>>>(wg, wgt, HID, DFF);
    transpose_k<<<dim3(HID / 64, DFF / 64, 8), 256, 0, stream>>>(wu, wut, HID, DFF);
    gateup2_k<<<dim3(16, DFF / 128, 8), 512, 0, stream>>>(hbf, wgt, wut, cnt, offs,
                                                          pair_token, act, 0, SL);
    transpose_k<<<dim3(DFF / 64, HID / 64, 8), 256, 0, stream>>>(wd, wgt, DFF, HID);
    down2_k<<<dim3(16, HID / 128, 8), 256, 0, stream>>>(act, wgt, cnt, offs,
                                                        pair_token, pair_w, out, 0, SL);
  } else {
    // per-expert fallback (~31.5 MB peak): wgt_e/wut_e slices reuse the wgt area
    unsigned short* wgtE = (unsigned short*)(ws + 19988736);
    unsigned short* wutE = (unsigned short*)(ws + 19988736 + 5767168);
    for (int e = 0; e < NEXP; ++e) {
      transpose_k<<<dim3(HID / 64, DFF / 64, 1), 256, 0, stream>>>(wg + e * SL, wgtE, HID, DFF);
      transpose_k<<<dim3(HID / 64, DFF / 64, 1), 256, 0, stream>>>(wu + e * SL, wutE, HID, DFF);
      gateup2_k<<<dim3(16, DFF / 128, 1), 512, 0, stream>>>(hbf, wgtE, wutE, cnt, offs,
                                                            pair_token, act, e, 0);
    }
    for (int e = 0; e < NEXP; ++e) {
      transpose_k<<<dim3(DFF / 64, HID / 64, 1), 256, 0, stream>>>(wd + e * SL, wgtE, DFF, HID);
      down2_k<<<dim3(16, HID / 128, 1), 256, 0, stream>>>(act, wgtE, cnt, offs,
                                                          pair_token, pair_w, out, e, 0);
    }
  }
}